// Round 8
// baseline (281.824 us; speedup 1.0000x reference)
//
#include <hip/hip_runtime.h>

// GaussianSplatting preprocess:
//   out = concat(positions [N,3], cov [N,3,3], alphas [N], sh [N,4]) flat f32
//   cov = R (S S^T) R^T = (R S)(R S)^T
//   sh  = [SH_C0, c1*SH_C1, c0*SH_C1, c2*SH_C1]
//
// v7: PHASE-ORDERED x LDS-COALESCED — the unmeasured cell of the 2x2.
// Ledger: v1 (interleaved+partial-line) 95us; v4b (interleaved+full-line)
// 97.5us; v6 (phased+partial-line phase D) 97-101us — all ~2.45 TB/s,
// compulsory 237 MB. Copy ubench (6.3 TB/s) = phased AND full-line.
// Hypothesis: per-channel DRAM efficiency needs BOTH few concurrent address
// streams AND full-line requests. Here every phase is 2-3 streams and every
// global access is a 1024B wave64 float4 instruction (8 full lines).
// Falsification: ~97us again -> 2x2 complete, declare platform ceiling.

#define SH_C0 0.282095f
#define SH_C1 0.488603f
#define BLK 256
#define GRID 2048

__global__ __launch_bounds__(BLK) void gs_kernel(
    const float* __restrict__ pos,
    const float* __restrict__ col,
    const float* __restrict__ alp,
    const float* __restrict__ Rm,
    const float* __restrict__ Sm,
    float* __restrict__ out_pos,   // [n*3]
    float* __restrict__ out_cov,   // [n*9]
    float* __restrict__ out_alp,   // [n]
    float* __restrict__ out_sh,    // [n*4]
    int n)
{
    // 27 KB: R (576 f4) | S (576 f4) | cov staging (576 f4); col reuses slot 0
    __shared__ float4 lds[1728];
    float4* ldsR = lds;
    float4* ldsS = lds + 576;
    float4* ldsC = lds + 1152;

    const int t = threadIdx.x;
    const int T = gridDim.x * blockDim.x;
    const int g = blockIdx.x * blockDim.x + t;
    const int full_tiles = n / BLK;       // 256-point tiles fully in-bounds

    // ---- Phase A: positions passthrough (pure 2-stream float4 copy) ----
    {
        const int nf = 3 * n;
        const int n4 = nf >> 2;
        const float4* src = (const float4*)pos;
        float4* dst = (float4*)out_pos;
        for (int u = g; u < n4; u += T) dst[u] = src[u];
        for (int u = (n4 << 2) + g; u < nf; u += T) out_pos[u] = pos[u];
    }

    // ---- Phase B: alphas passthrough (pure 2-stream float4 copy) ----
    {
        const int n4 = n >> 2;
        const float4* src = (const float4*)alp;
        float4* dst = (float4*)out_alp;
        for (int u = g; u < n4; u += T) dst[u] = src[u];
        for (int u = (n4 << 2) + g; u < n; u += T) out_alp[u] = alp[u];
    }

    // ---- Phase C: col -> sh, LDS-staged (full-line reads, float4 writes) ----
    {
        float4* sh4 = (float4*)out_sh;
        for (int tile = blockIdx.x; tile < full_tiles; tile += gridDim.x) {
            const int base = tile * BLK;
            const float4* C4 = (const float4*)(col + (size_t)base * 3);
            if (t < 192) lds[t] = C4[t];
            __syncthreads();
            const float* cc = (const float*)lds + t * 3;
            sh4[base + t] = make_float4(SH_C0, cc[1] * SH_C1,
                                        cc[0] * SH_C1, cc[2] * SH_C1);
            __syncthreads();
        }
        // scalar tail
        for (int i = full_tiles * BLK + g; i < n; i += T) {
            float c0 = col[3 * i + 0];
            float c1 = col[3 * i + 1];
            float c2 = col[3 * i + 2];
            sh4[i] = make_float4(SH_C0, c1 * SH_C1, c0 * SH_C1, c2 * SH_C1);
        }
    }

    // ---- Phase D: R,S -> cov, LDS-staged tiles (216 MB = 65% of bytes) ----
    for (int tile = blockIdx.x; tile < full_tiles; tile += gridDim.x) {
        const int base = tile * BLK;
        const float4* R4 = (const float4*)(Rm + (size_t)base * 9);
        const float4* S4 = (const float4*)(Sm + (size_t)base * 9);
        float4* OC4 = (float4*)(out_cov + (size_t)base * 9);

        // stage: each wave float4 instr = 1024 B = 8 full lines
        ldsR[t]       = R4[t];
        ldsR[t + 256] = R4[t + 256];
        ldsS[t]       = S4[t];
        ldsS[t + 256] = S4[t + 256];
        if (t < 64) {
            ldsR[t + 512] = R4[t + 512];
            ldsS[t + 512] = S4[t + 512];
        }
        __syncthreads();

        const float* rf = (const float*)ldsR + t * 9;
        const float* sf = (const float*)ldsS + t * 9;
        float r[9], s[9];
#pragma unroll
        for (int k = 0; k < 9; ++k) r[k] = rf[k];
#pragma unroll
        for (int k = 0; k < 9; ++k) s[k] = sf[k];

        float tm[9];  // T = R @ S
#pragma unroll
        for (int a = 0; a < 3; ++a)
#pragma unroll
            for (int b = 0; b < 3; ++b)
                tm[3 * a + b] = r[3 * a + 0] * s[0 + b]
                              + r[3 * a + 1] * s[3 + b]
                              + r[3 * a + 2] * s[6 + b];

        float* cf = (float*)ldsC + t * 9;
#pragma unroll
        for (int a = 0; a < 3; ++a)
#pragma unroll
            for (int b = 0; b < 3; ++b)
                cf[3 * a + b] = tm[3 * a + 0] * tm[3 * b + 0]
                              + tm[3 * a + 1] * tm[3 * b + 1]
                              + tm[3 * a + 2] * tm[3 * b + 2];
        __syncthreads();

        OC4[t]       = ldsC[t];
        OC4[t + 256] = ldsC[t + 256];
        if (t < 64) OC4[t + 512] = ldsC[t + 512];
        // next-iter staging writes ldsR/S (reads done before sync2 above);
        // ldsC overwrite happens after next-iter's first sync -> safe.
    }
    // scalar tail
    for (int i = full_tiles * BLK + g; i < n; i += T) {
        float r[9], s[9];
#pragma unroll
        for (int k = 0; k < 9; ++k) r[k] = Rm[9 * i + k];
#pragma unroll
        for (int k = 0; k < 9; ++k) s[k] = Sm[9 * i + k];

        float tm[9];
#pragma unroll
        for (int a = 0; a < 3; ++a)
#pragma unroll
            for (int b = 0; b < 3; ++b)
                tm[3 * a + b] = r[3 * a + 0] * s[0 + b]
                              + r[3 * a + 1] * s[3 + b]
                              + r[3 * a + 2] * s[6 + b];

#pragma unroll
        for (int a = 0; a < 3; ++a)
#pragma unroll
            for (int b = 0; b < 3; ++b)
                out_cov[9 * i + 3 * a + b] = tm[3 * a + 0] * tm[3 * b + 0]
                                           + tm[3 * a + 1] * tm[3 * b + 1]
                                           + tm[3 * a + 2] * tm[3 * b + 2];
    }
}

extern "C" void kernel_launch(void* const* d_in, const int* in_sizes, int n_in,
                              void* d_out, int out_size, void* d_ws, size_t ws_size,
                              hipStream_t stream) {
    const float* pos = (const float*)d_in[0];  // [N,3]
    const float* col = (const float*)d_in[1];  // [N,3]
    const float* alp = (const float*)d_in[2];  // [N]
    const float* Rm  = (const float*)d_in[3];  // [N,3,3]
    const float* Sm  = (const float*)d_in[4];  // [N,3,3]

    int n = in_sizes[0] / 3;

    float* out = (float*)d_out;
    float* out_pos = out;             // n*3
    float* out_cov = out + 3 * n;     // n*9
    float* out_alp = out + 12 * n;    // n
    float* out_sh  = out + 13 * n;    // n*4

    gs_kernel<<<GRID, BLK, 0, stream>>>(pos, col, alp, Rm, Sm,
                                        out_pos, out_cov, out_alp, out_sh, n);
}

// Round 9
// 271.873 us; speedup vs baseline: 1.0366x; 1.0366x over previous
//
#include <hip/hip_runtime.h>

// GaussianSplatting preprocess:
//   out = concat(positions [N,3], cov [N,3,3], alphas [N], sh [N,4]) flat f32
//   cov = R (S S^T) R^T = (R S)(R S)^T
//   sh  = [SH_C0, c1*SH_C1, c0*SH_C1, c2*SH_C1]
//
// v8 = v7 (phased + full-line LDS-coalesced) + NON-TEMPORAL LOADS on all
// inputs (stores stay plain/allocating).
// Ledger: v1/v4/v4b/v5b/v6/v7 all pinned at 2.40-2.48 TB/s hbm_bytes/dur
// (= ~1 line/cy/XCD at the L2<->fabric port) with compulsory 236 MB ->
// instruction-side levers exhausted. Last lever: MALL residency flip.
// Theory: nt loads keep the 200 MB input out of the MALL -> the 136 MB
// output stays dirty-resident -> next iteration's stores hit dirty MALL
// lines -> DRAM writes collapse; read-mostly DRAM streams may also dodge
// the mixed R/W turnaround penalty. All reads here are full 1024B wave
// requests, so no-allocate costs nothing on the read side.
// Decision rule: FETCH/WRITE bit-identical again -> nt is MALL-inert ->
// declare platform ceiling next round (revert to fastest variant).

#define SH_C0 0.282095f
#define SH_C1 0.488603f
#define BLK 256
#define GRID 2048

typedef float f32x4 __attribute__((ext_vector_type(4)));

__device__ __forceinline__ float4 nt_load4(const float4* p) {
    f32x4 w = __builtin_nontemporal_load((const f32x4*)p);
    return make_float4(w.x, w.y, w.z, w.w);
}
__device__ __forceinline__ float nt_load1(const float* p) {
    return __builtin_nontemporal_load(p);
}

__global__ __launch_bounds__(BLK) void gs_kernel(
    const float* __restrict__ pos,
    const float* __restrict__ col,
    const float* __restrict__ alp,
    const float* __restrict__ Rm,
    const float* __restrict__ Sm,
    float* __restrict__ out_pos,   // [n*3]
    float* __restrict__ out_cov,   // [n*9]
    float* __restrict__ out_alp,   // [n]
    float* __restrict__ out_sh,    // [n*4]
    int n)
{
    // 27 KB: R (576 f4) | S (576 f4) | cov staging (576 f4); col reuses slot 0
    __shared__ float4 lds[1728];
    float4* ldsR = lds;
    float4* ldsS = lds + 576;
    float4* ldsC = lds + 1152;

    const int t = threadIdx.x;
    const int T = gridDim.x * blockDim.x;
    const int g = blockIdx.x * blockDim.x + t;
    const int full_tiles = n / BLK;       // 256-point tiles fully in-bounds

    // ---- Phase A: positions passthrough (nt reads, plain writes) ----
    {
        const int nf = 3 * n;
        const int n4 = nf >> 2;
        const float4* src = (const float4*)pos;
        float4* dst = (float4*)out_pos;
        for (int u = g; u < n4; u += T) dst[u] = nt_load4(&src[u]);
        for (int u = (n4 << 2) + g; u < nf; u += T) out_pos[u] = nt_load1(&pos[u]);
    }

    // ---- Phase B: alphas passthrough ----
    {
        const int n4 = n >> 2;
        const float4* src = (const float4*)alp;
        float4* dst = (float4*)out_alp;
        for (int u = g; u < n4; u += T) dst[u] = nt_load4(&src[u]);
        for (int u = (n4 << 2) + g; u < n; u += T) out_alp[u] = nt_load1(&alp[u]);
    }

    // ---- Phase C: col -> sh, LDS-staged (nt full-line reads) ----
    {
        float4* sh4 = (float4*)out_sh;
        for (int tile = blockIdx.x; tile < full_tiles; tile += gridDim.x) {
            const int base = tile * BLK;
            const float4* C4 = (const float4*)(col + (size_t)base * 3);
            if (t < 192) lds[t] = nt_load4(&C4[t]);
            __syncthreads();
            const float* cc = (const float*)lds + t * 3;
            sh4[base + t] = make_float4(SH_C0, cc[1] * SH_C1,
                                        cc[0] * SH_C1, cc[2] * SH_C1);
            __syncthreads();
        }
        for (int i = full_tiles * BLK + g; i < n; i += T) {
            float c0 = nt_load1(&col[3 * i + 0]);
            float c1 = nt_load1(&col[3 * i + 1]);
            float c2 = nt_load1(&col[3 * i + 2]);
            sh4[i] = make_float4(SH_C0, c1 * SH_C1, c0 * SH_C1, c2 * SH_C1);
        }
    }

    // ---- Phase D: R,S -> cov, LDS-staged tiles (nt full-line reads) ----
    for (int tile = blockIdx.x; tile < full_tiles; tile += gridDim.x) {
        const int base = tile * BLK;
        const float4* R4 = (const float4*)(Rm + (size_t)base * 9);
        const float4* S4 = (const float4*)(Sm + (size_t)base * 9);
        float4* OC4 = (float4*)(out_cov + (size_t)base * 9);

        ldsR[t]       = nt_load4(&R4[t]);
        ldsR[t + 256] = nt_load4(&R4[t + 256]);
        ldsS[t]       = nt_load4(&S4[t]);
        ldsS[t + 256] = nt_load4(&S4[t + 256]);
        if (t < 64) {
            ldsR[t + 512] = nt_load4(&R4[t + 512]);
            ldsS[t + 512] = nt_load4(&S4[t + 512]);
        }
        __syncthreads();

        const float* rf = (const float*)ldsR + t * 9;
        const float* sf = (const float*)ldsS + t * 9;
        float r[9], s[9];
#pragma unroll
        for (int k = 0; k < 9; ++k) r[k] = rf[k];
#pragma unroll
        for (int k = 0; k < 9; ++k) s[k] = sf[k];

        float tm[9];  // T = R @ S
#pragma unroll
        for (int a = 0; a < 3; ++a)
#pragma unroll
            for (int b = 0; b < 3; ++b)
                tm[3 * a + b] = r[3 * a + 0] * s[0 + b]
                              + r[3 * a + 1] * s[3 + b]
                              + r[3 * a + 2] * s[6 + b];

        float* cf = (float*)ldsC + t * 9;
#pragma unroll
        for (int a = 0; a < 3; ++a)
#pragma unroll
            for (int b = 0; b < 3; ++b)
                cf[3 * a + b] = tm[3 * a + 0] * tm[3 * b + 0]
                              + tm[3 * a + 1] * tm[3 * b + 1]
                              + tm[3 * a + 2] * tm[3 * b + 2];
        __syncthreads();

        OC4[t]       = ldsC[t];
        OC4[t + 256] = ldsC[t + 256];
        if (t < 64) OC4[t + 512] = ldsC[t + 512];
    }
    // scalar tail
    for (int i = full_tiles * BLK + g; i < n; i += T) {
        float r[9], s[9];
#pragma unroll
        for (int k = 0; k < 9; ++k) r[k] = nt_load1(&Rm[9 * i + k]);
#pragma unroll
        for (int k = 0; k < 9; ++k) s[k] = nt_load1(&Sm[9 * i + k]);

        float tm[9];
#pragma unroll
        for (int a = 0; a < 3; ++a)
#pragma unroll
            for (int b = 0; b < 3; ++b)
                tm[3 * a + b] = r[3 * a + 0] * s[0 + b]
                              + r[3 * a + 1] * s[3 + b]
                              + r[3 * a + 2] * s[6 + b];

#pragma unroll
        for (int a = 0; a < 3; ++a)
#pragma unroll
            for (int b = 0; b < 3; ++b)
                out_cov[9 * i + 3 * a + b] = tm[3 * a + 0] * tm[3 * b + 0]
                                           + tm[3 * a + 1] * tm[3 * b + 1]
                                           + tm[3 * a + 2] * tm[3 * b + 2];
    }
}

extern "C" void kernel_launch(void* const* d_in, const int* in_sizes, int n_in,
                              void* d_out, int out_size, void* d_ws, size_t ws_size,
                              hipStream_t stream) {
    const float* pos = (const float*)d_in[0];  // [N,3]
    const float* col = (const float*)d_in[1];  // [N,3]
    const float* alp = (const float*)d_in[2];  // [N]
    const float* Rm  = (const float*)d_in[3];  // [N,3,3]
    const float* Sm  = (const float*)d_in[4];  // [N,3,3]

    int n = in_sizes[0] / 3;

    float* out = (float*)d_out;
    float* out_pos = out;             // n*3
    float* out_cov = out + 3 * n;     // n*9
    float* out_alp = out + 12 * n;    // n
    float* out_sh  = out + 13 * n;    // n*4

    gs_kernel<<<GRID, BLK, 0, stream>>>(pos, col, alp, Rm, Sm,
                                        out_pos, out_cov, out_alp, out_sh, n);
}

// Round 10
// 269.377 us; speedup vs baseline: 1.0462x; 1.0093x over previous
//
#include <hip/hip_runtime.h>

// GaussianSplatting preprocess:
//   out = concat(positions [N,3], cov [N,3,3], alphas [N], sh [N,4]) flat f32
//   cov = R (S S^T) R^T = (R S)(R S)^T
//   sh  = [SH_C0, c1*SH_C1, c0*SH_C1, c2*SH_C1]
//
// v9 = v8 (phased, LDS-coalesced, NT LOADS — the first lever that moved:
//      gs dropped ~97 -> <80.4 us, below the 80 us fill kernels) + MLP boost:
//   - phase D cov now overwrites each thread's OWN R-slice in LDS (self-owned,
//     no extra sync) -> LDS 27.6 KB -> 18 KB -> 8 blocks/CU (occ 42% -> ~100%)
//   - __launch_bounds__(256,8): VGPR was 44 <= 64, 32 waves/CU fits
//   - phase A unrolled x2: two independent nt loads in flight per wave
// Theory: nt loads are full-DRAM-latency (no L2/MALL allocation); with the
// allocation-policy bottleneck gone, latency hiding (waves x loads-in-flight)
// is the binding constraint. Fill kernels prove 6.7 TB/s is reachable.
// Decision rule: bench -10 us or better -> confirmed; null -> concurrency not
// binding, test full R/W bypass next; gs back in top-5 -> revert.

#define SH_C0 0.282095f
#define SH_C1 0.488603f
#define BLK 256
#define GRID 2048

typedef float f32x4 __attribute__((ext_vector_type(4)));

__device__ __forceinline__ float4 nt_load4(const float4* p) {
    f32x4 w = __builtin_nontemporal_load((const f32x4*)p);
    return make_float4(w.x, w.y, w.z, w.w);
}
__device__ __forceinline__ float nt_load1(const float* p) {
    return __builtin_nontemporal_load(p);
}

__global__ __launch_bounds__(BLK, 8) void gs_kernel(
    const float* __restrict__ pos,
    const float* __restrict__ col,
    const float* __restrict__ alp,
    const float* __restrict__ Rm,
    const float* __restrict__ Sm,
    float* __restrict__ out_pos,   // [n*3]
    float* __restrict__ out_cov,   // [n*9]
    float* __restrict__ out_alp,   // [n]
    float* __restrict__ out_sh,    // [n*4]
    int n)
{
    // 18 KB total: R/cov share one 9 KB buffer (self-owned overwrite), S 9 KB.
    __shared__ float4 ldsR[576];
    __shared__ float4 ldsS[576];

    const int t = threadIdx.x;
    const int T = gridDim.x * blockDim.x;
    const int g = blockIdx.x * blockDim.x + t;
    const int full_tiles = n / BLK;       // 256-point tiles fully in-bounds

    // ---- Phase A: positions passthrough (nt reads, x2 unroll for MLP) ----
    {
        const int nf = 3 * n;
        const int n4 = nf >> 2;
        const float4* src = (const float4*)pos;
        float4* dst = (float4*)out_pos;
        int u = g;
        for (; u + T < n4; u += 2 * T) {
            float4 a0 = nt_load4(&src[u]);
            float4 a1 = nt_load4(&src[u + T]);
            dst[u]     = a0;
            dst[u + T] = a1;
        }
        for (; u < n4; u += T) dst[u] = nt_load4(&src[u]);
        for (int w = (n4 << 2) + g; w < nf; w += T) out_pos[w] = nt_load1(&pos[w]);
    }

    // ---- Phase B: alphas passthrough (8 MB, single pass) ----
    {
        const int n4 = n >> 2;
        const float4* src = (const float4*)alp;
        float4* dst = (float4*)out_alp;
        for (int u = g; u < n4; u += T) dst[u] = nt_load4(&src[u]);
        for (int u = (n4 << 2) + g; u < n; u += T) out_alp[u] = nt_load1(&alp[u]);
    }

    // ---- Phase C: col -> sh, LDS-staged (nt full-line reads) ----
    {
        float4* sh4 = (float4*)out_sh;
        for (int tile = blockIdx.x; tile < full_tiles; tile += gridDim.x) {
            const int base = tile * BLK;
            const float4* C4 = (const float4*)(col + (size_t)base * 3);
            __syncthreads();               // protect previous iter's reads
            if (t < 192) ldsR[t] = nt_load4(&C4[t]);
            __syncthreads();
            const float* cc = (const float*)ldsR + t * 3;
            sh4[base + t] = make_float4(SH_C0, cc[1] * SH_C1,
                                        cc[0] * SH_C1, cc[2] * SH_C1);
        }
        for (int i = full_tiles * BLK + g; i < n; i += T) {
            float c0 = nt_load1(&col[3 * i + 0]);
            float c1 = nt_load1(&col[3 * i + 1]);
            float c2 = nt_load1(&col[3 * i + 2]);
            sh4[i] = make_float4(SH_C0, c1 * SH_C1, c0 * SH_C1, c2 * SH_C1);
        }
    }

    // ---- Phase D: R,S -> cov, LDS tiles; cov overwrites own R-slice ----
    for (int tile = blockIdx.x; tile < full_tiles; tile += gridDim.x) {
        const int base = tile * BLK;
        const float4* R4 = (const float4*)(Rm + (size_t)base * 9);
        const float4* S4 = (const float4*)(Sm + (size_t)base * 9);
        float4* OC4 = (float4*)(out_cov + (size_t)base * 9);

        __syncthreads();                   // protect previous tile's store-reads
        ldsR[t]       = nt_load4(&R4[t]);
        ldsR[t + 256] = nt_load4(&R4[t + 256]);
        ldsS[t]       = nt_load4(&S4[t]);
        ldsS[t + 256] = nt_load4(&S4[t + 256]);
        if (t < 64) {
            ldsR[t + 512] = nt_load4(&R4[t + 512]);
            ldsS[t + 512] = nt_load4(&S4[t + 512]);
        }
        __syncthreads();

        float* rf = (float*)ldsR + t * 9;          // this thread's R slice
        const float* sf = (const float*)ldsS + t * 9;
        float r[9], s[9];
#pragma unroll
        for (int k = 0; k < 9; ++k) r[k] = rf[k];
#pragma unroll
        for (int k = 0; k < 9; ++k) s[k] = sf[k];

        float tm[9];  // T = R @ S
#pragma unroll
        for (int a = 0; a < 3; ++a)
#pragma unroll
            for (int b = 0; b < 3; ++b)
                tm[3 * a + b] = r[3 * a + 0] * s[0 + b]
                              + r[3 * a + 1] * s[3 + b]
                              + r[3 * a + 2] * s[6 + b];

        // overwrite own R slice with cov (no cross-thread hazard)
#pragma unroll
        for (int a = 0; a < 3; ++a)
#pragma unroll
            for (int b = 0; b < 3; ++b)
                rf[3 * a + b] = tm[3 * a + 0] * tm[3 * b + 0]
                              + tm[3 * a + 1] * tm[3 * b + 1]
                              + tm[3 * a + 2] * tm[3 * b + 2];
        __syncthreads();

        OC4[t]       = ldsR[t];
        OC4[t + 256] = ldsR[t + 256];
        if (t < 64) OC4[t + 512] = ldsR[t + 512];
    }
    // scalar tail
    for (int i = full_tiles * BLK + g; i < n; i += T) {
        float r[9], s[9];
#pragma unroll
        for (int k = 0; k < 9; ++k) r[k] = nt_load1(&Rm[9 * i + k]);
#pragma unroll
        for (int k = 0; k < 9; ++k) s[k] = nt_load1(&Sm[9 * i + k]);

        float tm[9];
#pragma unroll
        for (int a = 0; a < 3; ++a)
#pragma unroll
            for (int b = 0; b < 3; ++b)
                tm[3 * a + b] = r[3 * a + 0] * s[0 + b]
                              + r[3 * a + 1] * s[3 + b]
                              + r[3 * a + 2] * s[6 + b];

#pragma unroll
        for (int a = 0; a < 3; ++a)
#pragma unroll
            for (int b = 0; b < 3; ++b)
                out_cov[9 * i + 3 * a + b] = tm[3 * a + 0] * tm[3 * b + 0]
                                           + tm[3 * a + 1] * tm[3 * b + 1]
                                           + tm[3 * a + 2] * tm[3 * b + 2];
    }
}

extern "C" void kernel_launch(void* const* d_in, const int* in_sizes, int n_in,
                              void* d_out, int out_size, void* d_ws, size_t ws_size,
                              hipStream_t stream) {
    const float* pos = (const float*)d_in[0];  // [N,3]
    const float* col = (const float*)d_in[1];  // [N,3]
    const float* alp = (const float*)d_in[2];  // [N]
    const float* Rm  = (const float*)d_in[3];  // [N,3,3]
    const float* Sm  = (const float*)d_in[4];  // [N,3,3]

    int n = in_sizes[0] / 3;

    float* out = (float*)d_out;
    float* out_pos = out;             // n*3
    float* out_cov = out + 3 * n;     // n*9
    float* out_alp = out + 12 * n;    // n
    float* out_sh  = out + 13 * n;    // n*4

    gs_kernel<<<GRID, BLK, 0, stream>>>(pos, col, alp, Rm, Sm,
                                        out_pos, out_cov, out_alp, out_sh, n);
}

// Round 11
// 264.955 us; speedup vs baseline: 1.0637x; 1.0167x over previous
//
#include <hip/hip_runtime.h>

// GaussianSplatting preprocess:
//   out = concat(positions [N,3], cov [N,3,3], alphas [N], sh [N,4]) flat f32
//   cov = R (S S^T) R^T = (R S)(R S)^T
//   sh  = [SH_C0, c1*SH_C1, c0*SH_C1, c2*SH_C1]
//
// v10 = v9 (phased, LDS-coalesced, NT LOADS, 18KB LDS / 8 blocks/CU)
//       + NT STORES on all outputs — FULL cache bypass. Clean A/B vs v9.
// Regime history: allocating loads capped the kernel at 2.45 TB/s for 8
// rounds; nt loads broke it (~97 -> <80 us). Stores still allocate in
// per-XCD L2 + MALL, and those allocations are provably useless (output
// never re-read; 544 MB inter-iteration resets thrash MALL regardless).
// R6's nt-store regression was measured in the allocating-LOAD regime
// (read-path-bound at 2.45) — doesn't transfer. Fill kernels prove pure
// write streams sustain 6.7 TB/s. DRAM floor for gs ~= 336 MB / 6.7 ~= 50us.
// Decision rule: better -> keep; gs back in top-5 (>80.4us) or bench
// regresses -> revert to v9, attack phase-D sync structure next.

#define SH_C0 0.282095f
#define SH_C1 0.488603f
#define BLK 256
#define GRID 2048

typedef float f32x4 __attribute__((ext_vector_type(4)));

__device__ __forceinline__ float4 nt_load4(const float4* p) {
    f32x4 w = __builtin_nontemporal_load((const f32x4*)p);
    return make_float4(w.x, w.y, w.z, w.w);
}
__device__ __forceinline__ float nt_load1(const float* p) {
    return __builtin_nontemporal_load(p);
}
__device__ __forceinline__ void nt_store4(float4* p, float4 v) {
    f32x4 w = { v.x, v.y, v.z, v.w };
    __builtin_nontemporal_store(w, (f32x4*)p);
}
__device__ __forceinline__ void nt_store1(float* p, float v) {
    __builtin_nontemporal_store(v, p);
}

__global__ __launch_bounds__(BLK, 8) void gs_kernel(
    const float* __restrict__ pos,
    const float* __restrict__ col,
    const float* __restrict__ alp,
    const float* __restrict__ Rm,
    const float* __restrict__ Sm,
    float* __restrict__ out_pos,   // [n*3]
    float* __restrict__ out_cov,   // [n*9]
    float* __restrict__ out_alp,   // [n]
    float* __restrict__ out_sh,    // [n*4]
    int n)
{
    // 18 KB total: R/cov share one 9 KB buffer (self-owned overwrite), S 9 KB.
    __shared__ float4 ldsR[576];
    __shared__ float4 ldsS[576];

    const int t = threadIdx.x;
    const int T = gridDim.x * blockDim.x;
    const int g = blockIdx.x * blockDim.x + t;
    const int full_tiles = n / BLK;       // 256-point tiles fully in-bounds

    // ---- Phase A: positions passthrough (nt read + nt write, x2 unroll) ----
    {
        const int nf = 3 * n;
        const int n4 = nf >> 2;
        const float4* src = (const float4*)pos;
        float4* dst = (float4*)out_pos;
        int u = g;
        for (; u + T < n4; u += 2 * T) {
            float4 a0 = nt_load4(&src[u]);
            float4 a1 = nt_load4(&src[u + T]);
            nt_store4(&dst[u],     a0);
            nt_store4(&dst[u + T], a1);
        }
        for (; u < n4; u += T) nt_store4(&dst[u], nt_load4(&src[u]));
        for (int w = (n4 << 2) + g; w < nf; w += T)
            nt_store1(&out_pos[w], nt_load1(&pos[w]));
    }

    // ---- Phase B: alphas passthrough ----
    {
        const int n4 = n >> 2;
        const float4* src = (const float4*)alp;
        float4* dst = (float4*)out_alp;
        for (int u = g; u < n4; u += T) nt_store4(&dst[u], nt_load4(&src[u]));
        for (int u = (n4 << 2) + g; u < n; u += T)
            nt_store1(&out_alp[u], nt_load1(&alp[u]));
    }

    // ---- Phase C: col -> sh, LDS-staged (nt full-line reads, nt writes) ----
    {
        float4* sh4 = (float4*)out_sh;
        for (int tile = blockIdx.x; tile < full_tiles; tile += gridDim.x) {
            const int base = tile * BLK;
            const float4* C4 = (const float4*)(col + (size_t)base * 3);
            __syncthreads();               // protect previous iter's reads
            if (t < 192) ldsR[t] = nt_load4(&C4[t]);
            __syncthreads();
            const float* cc = (const float*)ldsR + t * 3;
            nt_store4(&sh4[base + t],
                      make_float4(SH_C0, cc[1] * SH_C1,
                                  cc[0] * SH_C1, cc[2] * SH_C1));
        }
        for (int i = full_tiles * BLK + g; i < n; i += T) {
            float c0 = nt_load1(&col[3 * i + 0]);
            float c1 = nt_load1(&col[3 * i + 1]);
            float c2 = nt_load1(&col[3 * i + 2]);
            nt_store4(&sh4[i],
                      make_float4(SH_C0, c1 * SH_C1, c0 * SH_C1, c2 * SH_C1));
        }
    }

    // ---- Phase D: R,S -> cov, LDS tiles; cov overwrites own R-slice ----
    for (int tile = blockIdx.x; tile < full_tiles; tile += gridDim.x) {
        const int base = tile * BLK;
        const float4* R4 = (const float4*)(Rm + (size_t)base * 9);
        const float4* S4 = (const float4*)(Sm + (size_t)base * 9);
        float4* OC4 = (float4*)(out_cov + (size_t)base * 9);

        __syncthreads();                   // protect previous tile's store-reads
        ldsR[t]       = nt_load4(&R4[t]);
        ldsR[t + 256] = nt_load4(&R4[t + 256]);
        ldsS[t]       = nt_load4(&S4[t]);
        ldsS[t + 256] = nt_load4(&S4[t + 256]);
        if (t < 64) {
            ldsR[t + 512] = nt_load4(&R4[t + 512]);
            ldsS[t + 512] = nt_load4(&S4[t + 512]);
        }
        __syncthreads();

        float* rf = (float*)ldsR + t * 9;          // this thread's R slice
        const float* sf = (const float*)ldsS + t * 9;
        float r[9], s[9];
#pragma unroll
        for (int k = 0; k < 9; ++k) r[k] = rf[k];
#pragma unroll
        for (int k = 0; k < 9; ++k) s[k] = sf[k];

        float tm[9];  // T = R @ S
#pragma unroll
        for (int a = 0; a < 3; ++a)
#pragma unroll
            for (int b = 0; b < 3; ++b)
                tm[3 * a + b] = r[3 * a + 0] * s[0 + b]
                              + r[3 * a + 1] * s[3 + b]
                              + r[3 * a + 2] * s[6 + b];

        // overwrite own R slice with cov (no cross-thread hazard)
#pragma unroll
        for (int a = 0; a < 3; ++a)
#pragma unroll
            for (int b = 0; b < 3; ++b)
                rf[3 * a + b] = tm[3 * a + 0] * tm[3 * b + 0]
                              + tm[3 * a + 1] * tm[3 * b + 1]
                              + tm[3 * a + 2] * tm[3 * b + 2];
        __syncthreads();

        nt_store4(&OC4[t],       ldsR[t]);
        nt_store4(&OC4[t + 256], ldsR[t + 256]);
        if (t < 64) nt_store4(&OC4[t + 512], ldsR[t + 512]);
    }
    // scalar tail
    for (int i = full_tiles * BLK + g; i < n; i += T) {
        float r[9], s[9];
#pragma unroll
        for (int k = 0; k < 9; ++k) r[k] = nt_load1(&Rm[9 * i + k]);
#pragma unroll
        for (int k = 0; k < 9; ++k) s[k] = nt_load1(&Sm[9 * i + k]);

        float tm[9];
#pragma unroll
        for (int a = 0; a < 3; ++a)
#pragma unroll
            for (int b = 0; b < 3; ++b)
                tm[3 * a + b] = r[3 * a + 0] * s[0 + b]
                              + r[3 * a + 1] * s[3 + b]
                              + r[3 * a + 2] * s[6 + b];

#pragma unroll
        for (int a = 0; a < 3; ++a)
#pragma unroll
            for (int b = 0; b < 3; ++b)
                nt_store1(&out_cov[9 * i + 3 * a + b],
                          tm[3 * a + 0] * tm[3 * b + 0]
                        + tm[3 * a + 1] * tm[3 * b + 1]
                        + tm[3 * a + 2] * tm[3 * b + 2]);
    }
}

extern "C" void kernel_launch(void* const* d_in, const int* in_sizes, int n_in,
                              void* d_out, int out_size, void* d_ws, size_t ws_size,
                              hipStream_t stream) {
    const float* pos = (const float*)d_in[0];  // [N,3]
    const float* col = (const float*)d_in[1];  // [N,3]
    const float* alp = (const float*)d_in[2];  // [N]
    const float* Rm  = (const float*)d_in[3];  // [N,3,3]
    const float* Sm  = (const float*)d_in[4];  // [N,3,3]

    int n = in_sizes[0] / 3;

    float* out = (float*)d_out;
    float* out_pos = out;             // n*3
    float* out_cov = out + 3 * n;     // n*9
    float* out_alp = out + 12 * n;    // n
    float* out_sh  = out + 13 * n;    // n*4

    gs_kernel<<<GRID, BLK, 0, stream>>>(pos, col, alp, Rm, Sm,
                                        out_pos, out_cov, out_alp, out_sh, n);
}

// Round 12
// 264.893 us; speedup vs baseline: 1.0639x; 1.0002x over previous
//
#include <hip/hip_runtime.h>

// GaussianSplatting preprocess:
//   out = concat(positions [N,3], cov [N,3,3], alphas [N], sh [N,4]) flat f32
//   cov = R (S S^T) R^T = (R S)(R S)^T
//   sh  = [SH_C0, c1*SH_C1, c0*SH_C1, c2*SH_C1]
//
// v11 = v10 (phased, NT loads+stores = full cache bypass, 18KB LDS,
//       8 blocks/CU) with phases C/D rebuilt as WAVE-PRIVATE chunks:
//       each wave stages its own 64-point chunk (144 float4 R + 144 S,
//       contiguous full-line nt loads) into its own LDS region, computes,
//       writes back — intra-wave LDS ordering is guaranteed by in-order
//       lgkmcnt (compiler-inserted waits), so the kernel now has ZERO
//       __syncthreads. Previously ~15 block-wide barriers each exposed
//       worst-lane full-DRAM nt-load latency (~900cy) to all 4 waves.
// Arc: allocating loads capped at 2.45 TB/s (R0-R8); nt loads broke it;
// nt stores -4.4us (R11). Fill kernels: 6.7 TB/s => gs floor ~50us.
// Decision rule: null (+/-2us) -> barriers weren't binding -> declare
// roofline. absmax must stay at pass (0.25) — sync-bug tripwire.

#define SH_C0 0.282095f
#define SH_C1 0.488603f
#define BLK 256
#define GRID 2048

typedef float f32x4 __attribute__((ext_vector_type(4)));

__device__ __forceinline__ float4 nt_load4(const float4* p) {
    f32x4 w = __builtin_nontemporal_load((const f32x4*)p);
    return make_float4(w.x, w.y, w.z, w.w);
}
__device__ __forceinline__ float nt_load1(const float* p) {
    return __builtin_nontemporal_load(p);
}
__device__ __forceinline__ void nt_store4(float4* p, float4 v) {
    f32x4 w = { v.x, v.y, v.z, v.w };
    __builtin_nontemporal_store(w, (f32x4*)p);
}
__device__ __forceinline__ void nt_store1(float* p, float v) {
    __builtin_nontemporal_store(v, p);
}

__global__ __launch_bounds__(BLK, 8) void gs_kernel(
    const float* __restrict__ pos,
    const float* __restrict__ col,
    const float* __restrict__ alp,
    const float* __restrict__ Rm,
    const float* __restrict__ Sm,
    float* __restrict__ out_pos,   // [n*3]
    float* __restrict__ out_cov,   // [n*9]
    float* __restrict__ out_alp,   // [n]
    float* __restrict__ out_sh,    // [n*4]
    int n)
{
    // Per-wave LDS region: 288 float4 = R-chunk [0,144) + S-chunk [144,288).
    // 4 waves x 288 x 16 B = 18 KB -> 8 blocks/CU.
    __shared__ float4 lds[4][288];

    const int t    = threadIdx.x;
    const int lane = t & 63;
    const int wid  = t >> 6;
    const int T = gridDim.x * blockDim.x;
    const int g = blockIdx.x * blockDim.x + t;

    const int nWaves = gridDim.x * (BLK / 64);
    const int gw     = blockIdx.x * (BLK / 64) + wid;   // global wave id
    const int full_chunks = n / 64;                     // 64-point wave chunks

    // ---- Phase A: positions passthrough (nt r/w, x2 unroll) ----
    {
        const int nf = 3 * n;
        const int n4 = nf >> 2;
        const float4* src = (const float4*)pos;
        float4* dst = (float4*)out_pos;
        int u = g;
        for (; u + T < n4; u += 2 * T) {
            float4 a0 = nt_load4(&src[u]);
            float4 a1 = nt_load4(&src[u + T]);
            nt_store4(&dst[u],     a0);
            nt_store4(&dst[u + T], a1);
        }
        for (; u < n4; u += T) nt_store4(&dst[u], nt_load4(&src[u]));
        for (int w = (n4 << 2) + g; w < nf; w += T)
            nt_store1(&out_pos[w], nt_load1(&pos[w]));
    }

    // ---- Phase B: alphas passthrough ----
    {
        const int n4 = n >> 2;
        const float4* src = (const float4*)alp;
        float4* dst = (float4*)out_alp;
        for (int u = g; u < n4; u += T) nt_store4(&dst[u], nt_load4(&src[u]));
        for (int u = (n4 << 2) + g; u < n; u += T)
            nt_store1(&out_alp[u], nt_load1(&alp[u]));
    }

    // ---- Phase C: col -> sh, wave-private chunks (no barriers) ----
    {
        float4* sh4 = (float4*)out_sh;
        float4* bufC = lds[wid];
        for (int c = gw; c < full_chunks; c += nWaves) {
            const int base = c * 64;
            const float4* C4 = (const float4*)(col + (size_t)base * 3);
            // 64 pts x 3 f = 48 float4, full-line contiguous
            if (lane < 48) bufC[lane] = nt_load4(&C4[lane]);
            // intra-wave LDS write->read: ordered by lgkmcnt, no barrier
            const float* cc = (const float*)bufC + lane * 3;
            nt_store4(&sh4[base + lane],
                      make_float4(SH_C0, cc[1] * SH_C1,
                                  cc[0] * SH_C1, cc[2] * SH_C1));
        }
        for (int i = full_chunks * 64 + g; i < n; i += T) {
            float c0 = nt_load1(&col[3 * i + 0]);
            float c1 = nt_load1(&col[3 * i + 1]);
            float c2 = nt_load1(&col[3 * i + 2]);
            nt_store4(&sh4[i],
                      make_float4(SH_C0, c1 * SH_C1, c0 * SH_C1, c2 * SH_C1));
        }
    }

    // ---- Phase D: R,S -> cov, wave-private chunks (no barriers) ----
    {
        float4* bufR = lds[wid];         // 144 float4
        float4* bufS = lds[wid] + 144;   // 144 float4
        for (int c = gw; c < full_chunks; c += nWaves) {
            const int base = c * 64;
            const float4* R4 = (const float4*)(Rm + (size_t)base * 9);
            const float4* S4 = (const float4*)(Sm + (size_t)base * 9);
            float4* OC4 = (float4*)(out_cov + (size_t)base * 9);

            // stage 64 pts: 144 float4 each, contiguous full-line nt loads
            bufR[lane]      = nt_load4(&R4[lane]);
            bufR[lane + 64] = nt_load4(&R4[lane + 64]);
            bufS[lane]      = nt_load4(&S4[lane]);
            bufS[lane + 64] = nt_load4(&S4[lane + 64]);
            if (lane < 16) {
                bufR[lane + 128] = nt_load4(&R4[lane + 128]);
                bufS[lane + 128] = nt_load4(&S4[lane + 128]);
            }

            // intra-wave LDS ordering via lgkmcnt — no barrier needed
            float* rf = (float*)bufR + lane * 9;       // own R slice
            const float* sf = (const float*)bufS + lane * 9;
            float r[9], s[9];
#pragma unroll
            for (int k = 0; k < 9; ++k) r[k] = rf[k];
#pragma unroll
            for (int k = 0; k < 9; ++k) s[k] = sf[k];

            float tm[9];  // T = R @ S
#pragma unroll
            for (int a = 0; a < 3; ++a)
#pragma unroll
                for (int b = 0; b < 3; ++b)
                    tm[3 * a + b] = r[3 * a + 0] * s[0 + b]
                                  + r[3 * a + 1] * s[3 + b]
                                  + r[3 * a + 2] * s[6 + b];

            // cov overwrites own R slice (self-owned, wave-local)
#pragma unroll
            for (int a = 0; a < 3; ++a)
#pragma unroll
                for (int b = 0; b < 3; ++b)
                    rf[3 * a + b] = tm[3 * a + 0] * tm[3 * b + 0]
                                  + tm[3 * a + 1] * tm[3 * b + 1]
                                  + tm[3 * a + 2] * tm[3 * b + 2];

            // coalesced full-line nt writeback
            nt_store4(&OC4[lane],      bufR[lane]);
            nt_store4(&OC4[lane + 64], bufR[lane + 64]);
            if (lane < 16) nt_store4(&OC4[lane + 128], bufR[lane + 128]);
        }
        // scalar tail
        for (int i = full_chunks * 64 + g; i < n; i += T) {
            float r[9], s[9];
#pragma unroll
            for (int k = 0; k < 9; ++k) r[k] = nt_load1(&Rm[9 * i + k]);
#pragma unroll
            for (int k = 0; k < 9; ++k) s[k] = nt_load1(&Sm[9 * i + k]);

            float tm[9];
#pragma unroll
            for (int a = 0; a < 3; ++a)
#pragma unroll
                for (int b = 0; b < 3; ++b)
                    tm[3 * a + b] = r[3 * a + 0] * s[0 + b]
                                  + r[3 * a + 1] * s[3 + b]
                                  + r[3 * a + 2] * s[6 + b];

#pragma unroll
            for (int a = 0; a < 3; ++a)
#pragma unroll
                for (int b = 0; b < 3; ++b)
                    nt_store1(&out_cov[9 * i + 3 * a + b],
                              tm[3 * a + 0] * tm[3 * b + 0]
                            + tm[3 * a + 1] * tm[3 * b + 1]
                            + tm[3 * a + 2] * tm[3 * b + 2]);
        }
    }
}

extern "C" void kernel_launch(void* const* d_in, const int* in_sizes, int n_in,
                              void* d_out, int out_size, void* d_ws, size_t ws_size,
                              hipStream_t stream) {
    const float* pos = (const float*)d_in[0];  // [N,3]
    const float* col = (const float*)d_in[1];  // [N,3]
    const float* alp = (const float*)d_in[2];  // [N]
    const float* Rm  = (const float*)d_in[3];  // [N,3,3]
    const float* Sm  = (const float*)d_in[4];  // [N,3,3]

    int n = in_sizes[0] / 3;

    float* out = (float*)d_out;
    float* out_pos = out;             // n*3
    float* out_cov = out + 3 * n;     // n*9
    float* out_alp = out + 12 * n;    // n
    float* out_sh  = out + 13 * n;    // n*4

    gs_kernel<<<GRID, BLK, 0, stream>>>(pos, col, alp, Rm, Sm,
                                        out_pos, out_cov, out_alp, out_sh, n);
}